// Round 11
// baseline (160.396 us; speedup 1.0000x reference)
//
#include <hip/hip_runtime.h>

// ---------- types ----------
typedef __attribute__((ext_vector_type(4))) float float4_;
typedef __attribute__((ext_vector_type(4))) float f32x4;
typedef __attribute__((ext_vector_type(8))) int   i32x8;

#define NROWS 8192
#define NKEYS 16384
#define DDIM  256

// exp(x/T) == exp2(x * C_SC)
static constexpr float T_INV = (float)(1.0 / 0.07);
static constexpr float C_SC  = (float)(1.0 / (0.07 * 0.6931471805599453));

// ---------------------------------------------------------------------------
// fp8 chunk-image swizzle, 32B granularity (see r8 notes): byte offset of
// 32B-group g32 (0..7) of row r (0..255) in one 64KB chunk image.
// One function, both sides (prep global write + gemm ds_read) — rule #21.
// swz32(r+64,g) = swz32(r,g)+16384 -> colt stride 16384.
// ---------------------------------------------------------------------------
__device__ __forceinline__ int swz32(int r, int g32) {
  return (r << 8) + (((g32 ^ (r & 7)) & 7) << 5);
}

// ---------------------------------------------------------------------------
// Kernel 1: normalize rows; emit fp8 e4m3 (OCP, HW cvt):
//   qs8  [8192][256] fp8: normalized q scaled by C_SC (MFMA A), natural.
//   keys8: 64 chunk images of 64KB (pre-swizzled). 0..8191 = q, 8192.. = g.
//   Pterm[row] = dot_f32(q,g)/T ; diagsub[row] = exp2 of fp8-level qq diag.
// Also zeroes S and out[0] (out accumulated by finalize atomics).
// ---------------------------------------------------------------------------
__global__ __launch_bounds__(256) void prep_kernel(
    const float* __restrict__ h, const float* __restrict__ g,
    unsigned int* __restrict__ qs8, unsigned int* __restrict__ keys8,
    float* __restrict__ Pterm, float* __restrict__ diagsub,
    float* __restrict__ S, float* __restrict__ out)
{
  const int row  = blockIdx.x * 4 + (threadIdx.x >> 6);
  const int lane = threadIdx.x & 63;       // 4 dims each
  float4_ hv = *((const float4_*)h + row * 64 + lane);
  float4_ gv = *((const float4_*)g + row * 64 + lane);

  float ssh = hv.x*hv.x + hv.y*hv.y + hv.z*hv.z + hv.w*hv.w;
  float ssg = gv.x*gv.x + gv.y*gv.y + gv.z*gv.z + gv.w*gv.w;
#pragma unroll
  for (int m = 1; m < 64; m <<= 1) {
    ssh += __shfl_xor(ssh, m);
    ssg += __shfl_xor(ssg, m);
  }
  const float sh = 1.0f / fmaxf(sqrtf(ssh), 1e-8f);
  const float sg = 1.0f / fmaxf(sqrtf(ssg), 1e-8f);

  float qn[4] = { hv.x*sh, hv.y*sh, hv.z*sh, hv.w*sh };
  float gn[4] = { gv.x*sg, gv.y*sg, gv.z*sg, gv.w*sg };

  float pd = qn[0]*gn[0] + qn[1]*gn[1] + qn[2]*gn[2] + qn[3]*gn[3];

  // fp8 packs (RNE, saturating). word_sel / byte_sel must be literals.
  int pq = __builtin_amdgcn_cvt_pk_fp8_f32(qn[0], qn[1], 0, 0);
  pq     = __builtin_amdgcn_cvt_pk_fp8_f32(qn[2], qn[3], pq, 1);
  int ps = __builtin_amdgcn_cvt_pk_fp8_f32(qn[0]*C_SC, qn[1]*C_SC, 0, 0);
  ps     = __builtin_amdgcn_cvt_pk_fp8_f32(qn[2]*C_SC, qn[3]*C_SC, ps, 1);
  int pg = __builtin_amdgcn_cvt_pk_fp8_f32(gn[0], gn[1], 0, 0);
  pg     = __builtin_amdgcn_cvt_pk_fp8_f32(gn[2], gn[3], pg, 1);

  float dd =
      __builtin_amdgcn_cvt_f32_fp8(ps, 0) * __builtin_amdgcn_cvt_f32_fp8(pq, 0)
    + __builtin_amdgcn_cvt_f32_fp8(ps, 1) * __builtin_amdgcn_cvt_f32_fp8(pq, 1)
    + __builtin_amdgcn_cvt_f32_fp8(ps, 2) * __builtin_amdgcn_cvt_f32_fp8(pq, 2)
    + __builtin_amdgcn_cvt_f32_fp8(ps, 3) * __builtin_amdgcn_cvt_f32_fp8(pq, 3);

#pragma unroll
  for (int m = 1; m < 64; m <<= 1) {
    pd += __shfl_xor(pd, m);
    dd += __shfl_xor(dd, m);
  }

  qs8[(size_t)row * 64 + lane] = (unsigned int)ps;   // natural, coalesced

  char* kb = (char*)keys8;
  const int g32 = lane >> 3;               // 32B group 0..7
  const int sub = (lane & 7) << 2;         // dword within group
  {
    const int k = row;
    *(unsigned int*)(kb + (((size_t)(k >> 8)) << 16)
                     + swz32(k & 255, g32) + sub) = (unsigned int)pq;
  }
  {
    const int k = NROWS + row;
    *(unsigned int*)(kb + (((size_t)(k >> 8)) << 16)
                     + swz32(k & 255, g32) + sub) = (unsigned int)pg;
  }

  if (lane == 0) {
    Pterm[row]   = pd * T_INV;
    diagsub[row] = __builtin_amdgcn_exp2f(dd);
    S[row]       = 0.0f;
    if (row == 0) out[0] = 0.0f;           // finalize accumulates atomically
  }
}

// ---------------------------------------------------------------------------
// Kernel 2: fused MX-fp8 GEMM (K=128/instr, scale=1.0) + exp2 + row-sum.
// Grid 256 = 64 M-tiles (BM=128) x 4 key-slices (16 chunks of 256 keys).
// r8/r10 config (512,1): VGPR ~190, no spills, 2 waves/SIMD.
// vs r10: kk0/kk1 get SEPARATE accumulators (both C-in = 0) -> 8 fully
// independent MFMAs per colt instead of 4 dependent pairs. r10's null
// (VALU interleave) + cheap barriers left MFMA result-latency bubbles as
// the prime stall suspect: 4 chains x 34.5cy issue < plausible K=128
// result latency. Harvest: Sp += exp2(accA+accB) (dot = kk0+kk1 parts).
// ---------------------------------------------------------------------------
typedef __attribute__((address_space(1))) const unsigned int gu32;
typedef __attribute__((address_space(3))) unsigned int       lu32;

__global__ __launch_bounds__(512, 1) void nce_gemm(
    const unsigned int* __restrict__ qs8,
    const unsigned int* __restrict__ keys8,
    float* __restrict__ S)
{
  __shared__ __align__(16) char lds_k[2 * 65536];    // 128 KB double buffer

  const int tid  = threadIdx.x;
  const int wid  = tid >> 6;
  const int lane = tid & 63;
  const int l15  = lane & 15, l4 = lane >> 4;

  const int bid   = blockIdx.x;
  const int slice = bid & 3;               // constant per XCD
  const int mtile = bid >> 2;              // 0..63

  const int wm = wid >> 2;                 // 0..1
  const int wn = wid & 3;                  // 0..3
  const int m0 = mtile * 128 + wm * 64;

  // ---- A fragments: 32B of K per (mf, kk); K elem = kk*128 + l4*32 + j ----
  const char* qb = (const char*)qs8;
  i32x8 a8[4][2];
#pragma unroll
  for (int mf = 0; mf < 4; ++mf) {
    const char* rp = qb + (size_t)(m0 + mf * 16 + l15) * 256 + l4 * 32;
#pragma unroll
    for (int kk = 0; kk < 2; ++kk)
      a8[mf][kk] = *(const i32x8*)(rp + kk * 128);
  }

  // per-chunk loop-invariant ds_read offsets for colt==0 (colt adds 16384)
  const int rr0 = wn * 16 + l15;           // key row within chunk, colt 0
  int boff0[2];
#pragma unroll
  for (int kk = 0; kk < 2; ++kk)
    boff0[kk] = swz32(rr0, kk * 4 + l4);

  const f32x4 zero4 = { 0.f, 0.f, 0.f, 0.f };
  f32x4 accA[4][4], accB[4][4];            // [colt][mf], independent chains
  float Sp[4][4] = {};                     // [mf][q] row-sums

  const char* kbytes = (const char*)keys8;

  // stage chunk c (64KB image) linearly into LDS buffer c&1
  auto stage = [&](int c) {
    const char* src = kbytes + (((size_t)(slice * 16 + c)) << 16);
    char* dst = lds_k + (c & 1) * 65536;
#pragma unroll
    for (int i = 0; i < 8; ++i) {
      const int sub = (i << 3) + wid;      // 1KB sub-chunk 0..63
      __builtin_amdgcn_global_load_lds(
          (gu32*)(src + (sub << 10) + (lane << 4)),
          (lu32*)(dst + (sub << 10)),
          16, 0, 0);
    }
  };

  stage(0);
  for (int c = 0; c < 16; ++c) {
    __syncthreads();                       // chunk c landed; buf (c-1) free
    if (c + 1 < 16) stage(c + 1);          // async across whole chunk

    const char* lb = lds_k + (c & 1) * 65536;
#pragma unroll
    for (int colt = 0; colt < 4; ++colt) {
      i32x8 b80 = *(const i32x8*)(lb + boff0[0] + colt * 16384);
      i32x8 b81 = *(const i32x8*)(lb + boff0[1] + colt * 16384);

#pragma unroll
      for (int mf = 0; mf < 4; ++mf) {
        if (c > 0) {                       // harvest prev chunk (old accs)
#pragma unroll
          for (int q = 0; q < 4; ++q)
            Sp[mf][q] += __builtin_amdgcn_exp2f(accA[colt][mf][q]
                                              + accB[colt][mf][q]);
        }
        // cbsz=0 (A fmt fp8 e4m3), blgp=0 (B fmt fp8), scales 127 = x1.0
        accA[colt][mf] = __builtin_amdgcn_mfma_scale_f32_16x16x128_f8f6f4(
            a8[mf][0], b80, zero4, 0, 0, 0, 127, 0, 127);
        accB[colt][mf] = __builtin_amdgcn_mfma_scale_f32_16x16x128_f8f6f4(
            a8[mf][1], b81, zero4, 0, 0, 0, 127, 0, 127);
      }
    }
  }
#pragma unroll
  for (int ct = 0; ct < 4; ++ct)           // last chunk's harvest
#pragma unroll
    for (int mf = 0; mf < 4; ++mf)
#pragma unroll
      for (int q = 0; q < 4; ++q)
        Sp[mf][q] += __builtin_amdgcn_exp2f(accA[ct][mf][q] + accB[ct][mf][q]);

  // reduce across the 16 columns (lanes sharing l4), then one atomic/row
#pragma unroll
  for (int mf = 0; mf < 4; ++mf)
#pragma unroll
    for (int q = 0; q < 4; ++q) {
      float v = Sp[mf][q];
      v += __shfl_xor(v, 1); v += __shfl_xor(v, 2);
      v += __shfl_xor(v, 4); v += __shfl_xor(v, 8);
      Sp[mf][q] = v;
    }
  if (l15 == 0) {
#pragma unroll
    for (int mf = 0; mf < 4; ++mf)
#pragma unroll
      for (int q = 0; q < 4; ++q)
        atomicAdd(&S[m0 + mf * 16 + l4 * 4 + q], Sp[mf][q]);
  }
}

// ---------------------------------------------------------------------------
// Kernel 3: loss partials -> atomicAdd(out). 32 blocks x 256 thr = 1 row/thr.
// out zeroed by prep; f32 atomic reorder noise ~1e-6 rel, far under threshold.
// ---------------------------------------------------------------------------
__global__ __launch_bounds__(256) void finalize_kernel(
    const float* __restrict__ S, const float* __restrict__ Pterm,
    const float* __restrict__ diagsub, float* __restrict__ out)
{
  const int i = blockIdx.x * 256 + threadIdx.x;
  float v = S[i] - diagsub[i];
  float acc = logf(fmaxf(v, 1e-20f)) - Pterm[i];
#pragma unroll
  for (int m = 1; m < 64; m <<= 1) acc += __shfl_xor(acc, m);
  __shared__ float w[4];
  if ((threadIdx.x & 63) == 0) w[threadIdx.x >> 6] = acc;
  __syncthreads();
  if (threadIdx.x == 0)
    atomicAdd(out, (w[0] + w[1] + w[2] + w[3]) * (1.0f / (float)NROWS));
}

// ---------------------------------------------------------------------------
extern "C" void kernel_launch(void* const* d_in, const int* in_sizes, int n_in,
                              void* d_out, int out_size, void* d_ws, size_t ws_size,
                              hipStream_t stream) {
  const float* h  = (const float*)d_in[0];
  const float* hg = (const float*)d_in[1];

  char* ws = (char*)d_ws;
  const size_t OFF_QS   = 0;                      // 2 MB (8192*256 fp8)
  const size_t OFF_KEYS = (size_t)2 << 20;        // 4 MB (16384*256 fp8)
  const size_t OFF_P    = (size_t)6 << 20;        // 32 KB
  const size_t OFF_DIAG = OFF_P + 32 * 1024;      // 32 KB
  const size_t OFF_S    = OFF_DIAG + 32 * 1024;   // 32 KB
  const size_t NEED     = OFF_S + 32 * 1024;
  if (ws_size < NEED) return;

  unsigned int* qs8   = (unsigned int*)(ws + OFF_QS);
  unsigned int* keys8 = (unsigned int*)(ws + OFF_KEYS);
  float* Pterm   = (float*)(ws + OFF_P);
  float* diagsub = (float*)(ws + OFF_DIAG);
  float* S       = (float*)(ws + OFF_S);

  prep_kernel<<<2048, 256, 0, stream>>>(h, hg, qs8, keys8, Pterm, diagsub, S,
                                        (float*)d_out);
  nce_gemm<<<256, 512, 0, stream>>>(qs8, keys8, S);
  finalize_kernel<<<32, 256, 0, stream>>>(S, Pterm, diagsub, (float*)d_out);
}

// Round 12
// 54.374 us; speedup vs baseline: 2.9499x; 2.9499x over previous
//
#include <hip/hip_runtime.h>

// ---------- types ----------
typedef __attribute__((ext_vector_type(4))) float float4_;
typedef __attribute__((ext_vector_type(4))) float f32x4;
typedef __attribute__((ext_vector_type(8))) int   i32x8;

#define NROWS 8192
#define NKEYS 16384
#define DDIM  256

// exp(x/T) == exp2(x * C_SC)
static constexpr float T_INV = (float)(1.0 / 0.07);
static constexpr float C_SC  = (float)(1.0 / (0.07 * 0.6931471805599453));

// ---------------------------------------------------------------------------
// fp8 chunk-image swizzle, 32B granularity: byte offset of 32B-group g32
// (0..7) of row r (0..127) inside one 32KB chunk image (128 keys x 256 B).
// One function, both sides (prep global write + gemm ds_read) — rule #21.
// swz32(r+64,g) = swz32(r,g)+16384 (XOR uses r&7 only) -> colt stride 16384.
// Bank math unchanged from r8 (conflict-spread, 2-way free).
// ---------------------------------------------------------------------------
__device__ __forceinline__ int swz32(int r, int g32) {
  return (r << 8) + (((g32 ^ (r & 7)) & 7) << 5);
}

// ---------------------------------------------------------------------------
// Kernel 1: normalize rows; emit fp8 e4m3 (OCP, HW cvt):
//   qs8  [8192][256] fp8: normalized q scaled by C_SC (MFMA A), natural.
//   keys8: 128 chunk images of 32KB: key k -> image (k>>7), row k&127,
//          dword at swz32(r, d>>5) + (d&31). Keys 0..8191 = q, 8192.. = g.
//   Pterm[row] = dot_f32(q,g)/T ; diagsub[row] = exp2 of fp8-level qq diag.
// Also zeroes S and out[0] (finalize accumulates atomically).
// ---------------------------------------------------------------------------
__global__ __launch_bounds__(256) void prep_kernel(
    const float* __restrict__ h, const float* __restrict__ g,
    unsigned int* __restrict__ qs8, unsigned int* __restrict__ keys8,
    float* __restrict__ Pterm, float* __restrict__ diagsub,
    float* __restrict__ S, float* __restrict__ out)
{
  const int row  = blockIdx.x * 4 + (threadIdx.x >> 6);
  const int lane = threadIdx.x & 63;       // 4 dims each
  float4_ hv = *((const float4_*)h + row * 64 + lane);
  float4_ gv = *((const float4_*)g + row * 64 + lane);

  float ssh = hv.x*hv.x + hv.y*hv.y + hv.z*hv.z + hv.w*hv.w;
  float ssg = gv.x*gv.x + gv.y*gv.y + gv.z*gv.z + gv.w*gv.w;
#pragma unroll
  for (int m = 1; m < 64; m <<= 1) {
    ssh += __shfl_xor(ssh, m);
    ssg += __shfl_xor(ssg, m);
  }
  const float sh = 1.0f / fmaxf(sqrtf(ssh), 1e-8f);
  const float sg = 1.0f / fmaxf(sqrtf(ssg), 1e-8f);

  float qn[4] = { hv.x*sh, hv.y*sh, hv.z*sh, hv.w*sh };
  float gn[4] = { gv.x*sg, gv.y*sg, gv.z*sg, gv.w*sg };

  float pd = qn[0]*gn[0] + qn[1]*gn[1] + qn[2]*gn[2] + qn[3]*gn[3];

  // fp8 packs (RNE, saturating). word_sel / byte_sel must be literals.
  int pq = __builtin_amdgcn_cvt_pk_fp8_f32(qn[0], qn[1], 0, 0);
  pq     = __builtin_amdgcn_cvt_pk_fp8_f32(qn[2], qn[3], pq, 1);
  int ps = __builtin_amdgcn_cvt_pk_fp8_f32(qn[0]*C_SC, qn[1]*C_SC, 0, 0);
  ps     = __builtin_amdgcn_cvt_pk_fp8_f32(qn[2]*C_SC, qn[3]*C_SC, ps, 1);
  int pg = __builtin_amdgcn_cvt_pk_fp8_f32(gn[0], gn[1], 0, 0);
  pg     = __builtin_amdgcn_cvt_pk_fp8_f32(gn[2], gn[3], pg, 1);

  float dd =
      __builtin_amdgcn_cvt_f32_fp8(ps, 0) * __builtin_amdgcn_cvt_f32_fp8(pq, 0)
    + __builtin_amdgcn_cvt_f32_fp8(ps, 1) * __builtin_amdgcn_cvt_f32_fp8(pq, 1)
    + __builtin_amdgcn_cvt_f32_fp8(ps, 2) * __builtin_amdgcn_cvt_f32_fp8(pq, 2)
    + __builtin_amdgcn_cvt_f32_fp8(ps, 3) * __builtin_amdgcn_cvt_f32_fp8(pq, 3);

#pragma unroll
  for (int m = 1; m < 64; m <<= 1) {
    pd += __shfl_xor(pd, m);
    dd += __shfl_xor(dd, m);
  }

  qs8[(size_t)row * 64 + lane] = (unsigned int)ps;   // natural, coalesced

  char* kb = (char*)keys8;
  const int g32 = lane >> 3;               // 32B group 0..7
  const int sub = (lane & 7) << 2;         // dword within group
  {
    const int k = row;
    *(unsigned int*)(kb + (((size_t)(k >> 7)) << 15)
                     + swz32(k & 127, g32) + sub) = (unsigned int)pq;
  }
  {
    const int k = NROWS + row;
    *(unsigned int*)(kb + (((size_t)(k >> 7)) << 15)
                     + swz32(k & 127, g32) + sub) = (unsigned int)pg;
  }

  if (lane == 0) {
    Pterm[row]   = pd * T_INV;
    diagsub[row] = __builtin_amdgcn_exp2f(dd);
    S[row]       = 0.0f;
    if (row == 0) out[0] = 0.0f;           // finalize accumulates atomically
  }
}

// ---------------------------------------------------------------------------
// Kernel 2: fused MX-fp8 GEMM (K=128/instr, scale=1.0) + exp2 + row-sum.
// Grid 512 = 128 M-tiles (BM=64) x 4 key-slices (4096 keys = 32 chunks of
// 128). slice = bid & 3 (XCD-resident: bid%8 fixes bid&3 per XCD).
// vs r8: BM 128->64 shrinks per-thread state to ~100 regs (a8 32 + acc 16 +
// Sp 8 + b8 16 + misc) so launch_bounds(512,4) fits WITHOUT spilling (r9's
// failure: 190 regs > 128 budget -> scratch, r11 same). 64KB LDS/block ->
// TWO independent blocks/CU = 16 waves/CU with DE-CORRELATED phases: when
// one block's waves MFMA-burst, the other's harvest/stage VALU fills the
// gap. r8/r10 pipe-sum evidence (32%+30%+22% ~= wall, lockstep) says this
// phase overlap is the remaining 2-3x.
// ---------------------------------------------------------------------------
typedef __attribute__((address_space(1))) const unsigned int gu32;
typedef __attribute__((address_space(3))) unsigned int       lu32;

__global__ __launch_bounds__(512, 4) void nce_gemm(
    const unsigned int* __restrict__ qs8,
    const unsigned int* __restrict__ keys8,
    float* __restrict__ S)
{
  __shared__ __align__(16) char lds_k[2 * 32768];    // 64 KB double buffer

  const int tid  = threadIdx.x;
  const int wid  = tid >> 6;
  const int lane = tid & 63;
  const int l15  = lane & 15, l4 = lane >> 4;

  const int bid   = blockIdx.x;
  const int slice = bid & 3;               // constant per XCD
  const int mtile = bid >> 2;              // 0..127

  const int wm = wid >> 2;                 // 0..1
  const int wn = wid & 3;                  // 0..3
  const int m0 = mtile * 64 + wm * 32;

  // ---- A fragments: 32B of K per (mf, kk); K elem = kk*128 + l4*32 + j ----
  const char* qb = (const char*)qs8;
  i32x8 a8[2][2];
#pragma unroll
  for (int mf = 0; mf < 2; ++mf) {
    const char* rp = qb + (size_t)(m0 + mf * 16 + l15) * 256 + l4 * 32;
#pragma unroll
    for (int kk = 0; kk < 2; ++kk)
      a8[mf][kk] = *(const i32x8*)(rp + kk * 128);
  }

  // per-chunk loop-invariant ds_read offsets for colt==0 (colt adds 16384)
  const int rr0 = wn * 16 + l15;           // key row within chunk, colt 0
  int boff0[2];
#pragma unroll
  for (int kk = 0; kk < 2; ++kk)
    boff0[kk] = swz32(rr0, kk * 4 + l4);

  const f32x4 zero4 = { 0.f, 0.f, 0.f, 0.f };
  f32x4 acc[2][2];                         // [colt][mf]
  float Sp[2][4] = {};                     // [mf][q] row-sums

  const char* kbytes = (const char*)keys8;

  // stage chunk c (32KB image) linearly into LDS buffer c&1
  auto stage = [&](int c) {
    const char* src = kbytes + (((size_t)(slice * 32 + c)) << 15);
    char* dst = lds_k + (c & 1) * 32768;
#pragma unroll
    for (int i = 0; i < 4; ++i) {
      const int sub = (i << 3) + wid;      // 1KB sub-chunk 0..31
      __builtin_amdgcn_global_load_lds(
          (gu32*)(src + (sub << 10) + (lane << 4)),
          (lu32*)(dst + (sub << 10)),
          16, 0, 0);
    }
  };

  stage(0);
  for (int c = 0; c < 32; ++c) {
    __syncthreads();                       // chunk c landed; buf (c-1) free
    if (c + 1 < 32) stage(c + 1);          // async across whole chunk

    const char* lb = lds_k + (c & 1) * 32768;
#pragma unroll
    for (int colt = 0; colt < 2; ++colt) {
      i32x8 b80 = *(const i32x8*)(lb + boff0[0] + colt * 16384);
      i32x8 b81 = *(const i32x8*)(lb + boff0[1] + colt * 16384);

#pragma unroll
      for (int mf = 0; mf < 2; ++mf) {
        if (c > 0) {                       // harvest prev chunk (old acc)
#pragma unroll
          for (int q = 0; q < 4; ++q)
            Sp[mf][q] += __builtin_amdgcn_exp2f(acc[colt][mf][q]);
        }
        // cbsz=0 (A fmt fp8 e4m3), blgp=0 (B fmt fp8), scales 127 = x1.0
        f32x4 t = __builtin_amdgcn_mfma_scale_f32_16x16x128_f8f6f4(
            a8[mf][0], b80, zero4, 0, 0, 0, 127, 0, 127);
        acc[colt][mf] = __builtin_amdgcn_mfma_scale_f32_16x16x128_f8f6f4(
            a8[mf][1], b81, t, 0, 0, 0, 127, 0, 127);
      }
    }
  }
#pragma unroll
  for (int ct = 0; ct < 2; ++ct)           // last chunk's harvest
#pragma unroll
    for (int mf = 0; mf < 2; ++mf)
#pragma unroll
      for (int q = 0; q < 4; ++q)
        Sp[mf][q] += __builtin_amdgcn_exp2f(acc[ct][mf][q]);

  // reduce across the 16 columns (lanes sharing l4), then one atomic/row
#pragma unroll
  for (int mf = 0; mf < 2; ++mf)
#pragma unroll
    for (int q = 0; q < 4; ++q) {
      float v = Sp[mf][q];
      v += __shfl_xor(v, 1); v += __shfl_xor(v, 2);
      v += __shfl_xor(v, 4); v += __shfl_xor(v, 8);
      Sp[mf][q] = v;
    }
  if (l15 == 0) {
#pragma unroll
    for (int mf = 0; mf < 2; ++mf)
#pragma unroll
      for (int q = 0; q < 4; ++q)
        atomicAdd(&S[m0 + mf * 16 + l4 * 4 + q], Sp[mf][q]);
  }
}

// ---------------------------------------------------------------------------
// Kernel 3: loss partials -> atomicAdd(out). 32 blocks x 256 thr = 1 row/thr.
// out zeroed by prep; f32 atomic reorder noise ~1e-6 rel, far under threshold.
// ---------------------------------------------------------------------------
__global__ __launch_bounds__(256) void finalize_kernel(
    const float* __restrict__ S, const float* __restrict__ Pterm,
    const float* __restrict__ diagsub, float* __restrict__ out)
{
  const int i = blockIdx.x * 256 + threadIdx.x;
  float v = S[i] - diagsub[i];
  float acc = logf(fmaxf(v, 1e-20f)) - Pterm[i];
#pragma unroll
  for (int m = 1; m < 64; m <<= 1) acc += __shfl_xor(acc, m);
  __shared__ float w[4];
  if ((threadIdx.x & 63) == 0) w[threadIdx.x >> 6] = acc;
  __syncthreads();
  if (threadIdx.x == 0)
    atomicAdd(out, (w[0] + w[1] + w[2] + w[3]) * (1.0f / (float)NROWS));
}

// ---------------------------------------------------------------------------
extern "C" void kernel_launch(void* const* d_in, const int* in_sizes, int n_in,
                              void* d_out, int out_size, void* d_ws, size_t ws_size,
                              hipStream_t stream) {
  const float* h  = (const float*)d_in[0];
  const float* hg = (const float*)d_in[1];

  char* ws = (char*)d_ws;
  const size_t OFF_QS   = 0;                      // 2 MB (8192*256 fp8)
  const size_t OFF_KEYS = (size_t)2 << 20;        // 4 MB (16384*256 fp8)
  const size_t OFF_P    = (size_t)6 << 20;        // 32 KB
  const size_t OFF_DIAG = OFF_P + 32 * 1024;      // 32 KB
  const size_t OFF_S    = OFF_DIAG + 32 * 1024;   // 32 KB
  const size_t NEED     = OFF_S + 32 * 1024;
  if (ws_size < NEED) return;

  unsigned int* qs8   = (unsigned int*)(ws + OFF_QS);
  unsigned int* keys8 = (unsigned int*)(ws + OFF_KEYS);
  float* Pterm   = (float*)(ws + OFF_P);
  float* diagsub = (float*)(ws + OFF_DIAG);
  float* S       = (float*)(ws + OFF_S);

  prep_kernel<<<2048, 256, 0, stream>>>(h, hg, qs8, keys8, Pterm, diagsub, S,
                                        (float*)d_out);
  nce_gemm<<<512, 512, 0, stream>>>(qs8, keys8, S);
  finalize_kernel<<<32, 256, 0, stream>>>(S, Pterm, diagsub, (float*)d_out);
}

// Round 13
// 52.389 us; speedup vs baseline: 3.0616x; 1.0379x over previous
//
#include <hip/hip_runtime.h>

// ---------- types ----------
typedef __attribute__((ext_vector_type(4))) float float4_;
typedef __attribute__((ext_vector_type(4))) float f32x4;
typedef __attribute__((ext_vector_type(8))) int   i32x8;

#define NROWS 8192
#define NKEYS 16384
#define DDIM  256

// exp(x/T) == exp2(x * C_SC)
static constexpr float T_INV = (float)(1.0 / 0.07);
static constexpr float C_SC  = (float)(1.0 / (0.07 * 0.6931471805599453));

// ---------------------------------------------------------------------------
// Fragment-linear key layout (NO LDS, NO swizzle): key-group G = 16 keys.
// Byte address of the 32B B-fragment of (G, kk, lane):
//     G*4096 + kk*2048 + lane*32
// where lane = l4*16 + l15 holds key (G*16 + l15), dims [kk*128+l4*32, +32)
// — exactly the 16x16x128 B operand convention verified in r8-r12.
// A wave's load is lane-contiguous: 2KB per i32x8 -> perfectly coalesced.
// prep writes it, gemm reads it (rule #21: one convention, both sides).
// ---------------------------------------------------------------------------

// ---------------------------------------------------------------------------
// Kernel 1: normalize rows; emit fp8 e4m3 (OCP, HW cvt):
//   qs8  [8192][256] fp8: normalized q scaled by C_SC (MFMA A), natural.
//   keys8: fragment-linear (above). Keys 0..8191 = q, 8192..16383 = g.
//   Pterm[row] = dot_f32(q,g)/T ; diagsub[row] = exp2 of fp8-level qq diag.
// Also zeroes S and out[0].
// ---------------------------------------------------------------------------
__global__ __launch_bounds__(256) void prep_kernel(
    const float* __restrict__ h, const float* __restrict__ g,
    unsigned int* __restrict__ qs8, unsigned int* __restrict__ keys8,
    float* __restrict__ Pterm, float* __restrict__ diagsub,
    float* __restrict__ S, float* __restrict__ out)
{
  const int row  = blockIdx.x * 4 + (threadIdx.x >> 6);
  const int lane = threadIdx.x & 63;       // 4 dims each
  float4_ hv = *((const float4_*)h + row * 64 + lane);
  float4_ gv = *((const float4_*)g + row * 64 + lane);

  float ssh = hv.x*hv.x + hv.y*hv.y + hv.z*hv.z + hv.w*hv.w;
  float ssg = gv.x*gv.x + gv.y*gv.y + gv.z*gv.z + gv.w*gv.w;
#pragma unroll
  for (int m = 1; m < 64; m <<= 1) {
    ssh += __shfl_xor(ssh, m);
    ssg += __shfl_xor(ssg, m);
  }
  const float sh = 1.0f / fmaxf(sqrtf(ssh), 1e-8f);
  const float sg = 1.0f / fmaxf(sqrtf(ssg), 1e-8f);

  float qn[4] = { hv.x*sh, hv.y*sh, hv.z*sh, hv.w*sh };
  float gn[4] = { gv.x*sg, gv.y*sg, gv.z*sg, gv.w*sg };

  float pd = qn[0]*gn[0] + qn[1]*gn[1] + qn[2]*gn[2] + qn[3]*gn[3];

  // fp8 packs (RNE, saturating). word_sel / byte_sel must be literals.
  int pq = __builtin_amdgcn_cvt_pk_fp8_f32(qn[0], qn[1], 0, 0);
  pq     = __builtin_amdgcn_cvt_pk_fp8_f32(qn[2], qn[3], pq, 1);
  int ps = __builtin_amdgcn_cvt_pk_fp8_f32(qn[0]*C_SC, qn[1]*C_SC, 0, 0);
  ps     = __builtin_amdgcn_cvt_pk_fp8_f32(qn[2]*C_SC, qn[3]*C_SC, ps, 1);
  int pg = __builtin_amdgcn_cvt_pk_fp8_f32(gn[0], gn[1], 0, 0);
  pg     = __builtin_amdgcn_cvt_pk_fp8_f32(gn[2], gn[3], pg, 1);

  float dd =
      __builtin_amdgcn_cvt_f32_fp8(ps, 0) * __builtin_amdgcn_cvt_f32_fp8(pq, 0)
    + __builtin_amdgcn_cvt_f32_fp8(ps, 1) * __builtin_amdgcn_cvt_f32_fp8(pq, 1)
    + __builtin_amdgcn_cvt_f32_fp8(ps, 2) * __builtin_amdgcn_cvt_f32_fp8(pq, 2)
    + __builtin_amdgcn_cvt_f32_fp8(ps, 3) * __builtin_amdgcn_cvt_f32_fp8(pq, 3);

#pragma unroll
  for (int m = 1; m < 64; m <<= 1) {
    pd += __shfl_xor(pd, m);
    dd += __shfl_xor(dd, m);
  }

  qs8[(size_t)row * 64 + lane] = (unsigned int)ps;   // natural, coalesced

  // fragment-linear key writes: this lane's dword = dims [lane*4, lane*4+4)
  // kk = lane>>5 ; l4 = (lane>>3)&3 ; inner byte = (lane&7)*4
  char* kb = (char*)keys8;
  const int foff = ((lane >> 5) << 11) + (((lane >> 3) & 3) << 9)
                 + ((lane & 7) << 2);
  {
    const int k = row;                     // q keys
    *(unsigned int*)(kb + (((size_t)(k >> 4)) << 12) + foff
                     + ((k & 15) << 5)) = (unsigned int)pq;
  }
  {
    const int k = NROWS + row;             // g keys
    *(unsigned int*)(kb + (((size_t)(k >> 4)) << 12) + foff
                     + ((k & 15) << 5)) = (unsigned int)pg;
  }

  if (lane == 0) {
    Pterm[row]   = pd * T_INV;
    diagsub[row] = __builtin_amdgcn_exp2f(dd);
    S[row]       = 0.0f;
    if (row == 0) out[0] = 0.0f;           // finalize accumulates atomically
  }
}

// ---------------------------------------------------------------------------
// Kernel 2: fused MX-fp8 GEMM (K=128/instr) + exp2 + row-sum — NO LDS
// staging, NO main-loop barriers. Row-sum-only output means no wave needs a
// full C tile: each wave privately owns 128 M-rows x 512 keys and streams B
// fragments straight from L2 into registers (fragment-linear layout, fully
// coalesced). r12 evidence: LDS pipe (staging+reads, 2x redundant) became
// the top consumer while waves moved in lockstep; removing LDS+barriers
// removes both. B L2 traffic = 256MB = 28 B/cy/CU, half the L2 ceiling ->
// MFMA-bound (floor 14.7us). 8 independent drifting waves/CU.
// Grid 256 = 64 mtiles x 4 slices; slice = bid&3 (XCD L2-resident, 1MB).
// ---------------------------------------------------------------------------
__global__ __launch_bounds__(512, 1) void nce_gemm(
    const unsigned int* __restrict__ qs8,
    const unsigned int* __restrict__ keys8,
    float* __restrict__ S)
{
  __shared__ float sred[128];              // end-of-kernel reduce only

  const int tid  = threadIdx.x;
  const int wid  = tid >> 6;
  const int lane = tid & 63;
  const int l15  = lane & 15, l4 = lane >> 4;

  const int bid   = blockIdx.x;
  const int slice = bid & 3;               // constant per XCD
  const int mtile = bid >> 2;              // 0..63
  const int m0    = mtile * 128;           // all 8 waves share these rows

  if (tid < 128) sred[tid] = 0.0f;

  // ---- A fragments: 8 mf x 2 kk x 32B ; K elem = kk*128 + l4*32 + j ----
  const char* qb = (const char*)qs8;
  i32x8 a8[8][2];
#pragma unroll
  for (int mf = 0; mf < 8; ++mf) {
    const char* rp = qb + (size_t)(m0 + mf * 16 + l15) * 256 + l4 * 32;
#pragma unroll
    for (int kk = 0; kk < 2; ++kk)
      a8[mf][kk] = *(const i32x8*)(rp + kk * 128);
  }

  const f32x4 zero4 = { 0.f, 0.f, 0.f, 0.f };
  f32x4 acc[8];
  float Sp[8][4] = {};                     // [mf][q] row-sums

  // wave's private key range: 512 keys = 32 groups of 16
  const char* kp = (const char*)keys8
      + (((size_t)(slice * 256 + wid * 32)) << 12) + (size_t)lane * 32;

#pragma unroll 2
  for (int g = 0; g < 32; ++g) {
    i32x8 b0 = *(const i32x8*)(kp + ((size_t)g << 12));
    i32x8 b1 = *(const i32x8*)(kp + ((size_t)g << 12) + 2048);

    if (g > 0) {                           // harvest prev group (old acc)
#pragma unroll
      for (int mf = 0; mf < 8; ++mf)
#pragma unroll
        for (int q = 0; q < 4; ++q)
          Sp[mf][q] += __builtin_amdgcn_exp2f(acc[mf][q]);
    }

    // cbsz=0 (A fmt fp8 e4m3), blgp=0 (B fmt fp8), scales 127 = x1.0
#pragma unroll
    for (int mf = 0; mf < 8; ++mf) {
      f32x4 t = __builtin_amdgcn_mfma_scale_f32_16x16x128_f8f6f4(
          a8[mf][0], b0, zero4, 0, 0, 0, 127, 0, 127);
      acc[mf] = __builtin_amdgcn_mfma_scale_f32_16x16x128_f8f6f4(
          a8[mf][1], b1, t, 0, 0, 0, 127, 0, 127);
    }
  }
#pragma unroll
  for (int mf = 0; mf < 8; ++mf)           // last group's harvest
#pragma unroll
    for (int q = 0; q < 4; ++q)
      Sp[mf][q] += __builtin_amdgcn_exp2f(acc[mf][q]);

  // reduce across the 16 key-columns (lanes sharing l4)
#pragma unroll
  for (int mf = 0; mf < 8; ++mf)
#pragma unroll
    for (int q = 0; q < 4; ++q) {
      float v = Sp[mf][q];
      v += __shfl_xor(v, 1); v += __shfl_xor(v, 2);
      v += __shfl_xor(v, 4); v += __shfl_xor(v, 8);
      Sp[mf][q] = v;
    }

  // block-level reduce in LDS (8 waves share the same 128 rows), then
  // one global atomic per row (4 slices -> 4 atomics/row total).
  __syncthreads();                         // sred init visible
  if (l15 == 0) {
#pragma unroll
    for (int mf = 0; mf < 8; ++mf)
#pragma unroll
      for (int q = 0; q < 4; ++q)
        atomicAdd(&sred[mf * 16 + l4 * 4 + q], Sp[mf][q]);
  }
  __syncthreads();
  if (tid < 128) atomicAdd(&S[m0 + tid], sred[tid]);
}

// ---------------------------------------------------------------------------
// Kernel 3: loss partials -> atomicAdd(out). 32 blocks x 256 thr = 1 row/thr.
// ---------------------------------------------------------------------------
__global__ __launch_bounds__(256) void finalize_kernel(
    const float* __restrict__ S, const float* __restrict__ Pterm,
    const float* __restrict__ diagsub, float* __restrict__ out)
{
  const int i = blockIdx.x * 256 + threadIdx.x;
  float v = S[i] - diagsub[i];
  float acc = logf(fmaxf(v, 1e-20f)) - Pterm[i];
#pragma unroll
  for (int m = 1; m < 64; m <<= 1) acc += __shfl_xor(acc, m);
  __shared__ float w[4];
  if ((threadIdx.x & 63) == 0) w[threadIdx.x >> 6] = acc;
  __syncthreads();
  if (threadIdx.x == 0)
    atomicAdd(out, (w[0] + w[1] + w[2] + w[3]) * (1.0f / (float)NROWS));
}

// ---------------------------------------------------------------------------
extern "C" void kernel_launch(void* const* d_in, const int* in_sizes, int n_in,
                              void* d_out, int out_size, void* d_ws, size_t ws_size,
                              hipStream_t stream) {
  const float* h  = (const float*)d_in[0];
  const float* hg = (const float*)d_in[1];

  char* ws = (char*)d_ws;
  const size_t OFF_QS   = 0;                      // 2 MB (8192*256 fp8)
  const size_t OFF_KEYS = (size_t)2 << 20;        // 4 MB (16384*256 fp8)
  const size_t OFF_P    = (size_t)6 << 20;        // 32 KB
  const size_t OFF_DIAG = OFF_P + 32 * 1024;      // 32 KB
  const size_t OFF_S    = OFF_DIAG + 32 * 1024;   // 32 KB
  const size_t NEED     = OFF_S + 32 * 1024;
  if (ws_size < NEED) return;

  unsigned int* qs8   = (unsigned int*)(ws + OFF_QS);
  unsigned int* keys8 = (unsigned int*)(ws + OFF_KEYS);
  float* Pterm   = (float*)(ws + OFF_P);
  float* diagsub = (float*)(ws + OFF_DIAG);
  float* S       = (float*)(ws + OFF_S);

  prep_kernel<<<2048, 256, 0, stream>>>(h, hg, qs8, keys8, Pterm, diagsub, S,
                                        (float*)d_out);
  nce_gemm<<<256, 512, 0, stream>>>(qs8, keys8, S);
  finalize_kernel<<<32, 256, 0, stream>>>(S, Pterm, diagsub, (float*)d_out);
}

// Round 15
// 51.560 us; speedup vs baseline: 3.1108x; 1.0161x over previous
//
#include <hip/hip_runtime.h>

// ---------- types ----------
typedef __attribute__((ext_vector_type(4))) float float4_;
typedef __attribute__((ext_vector_type(4))) float f32x4;
typedef __attribute__((ext_vector_type(8))) int   i32x8;

#define NROWS 8192
#define NKEYS 16384
#define DDIM  256

// exp(x/T) == exp2(x * C_SC)
static constexpr float T_INV = (float)(1.0 / 0.07);
static constexpr float C_SC  = (float)(1.0 / (0.07 * 0.6931471805599453));

// ---------------------------------------------------------------------------
// Fragment-linear key layout (NO LDS, NO swizzle): key-group G = 16 keys.
// Byte address of the 32B B-fragment of (G, kk, lane):
//     G*4096 + kk*2048 + lane*32
// lane = l4*16 + l15 holds key (G*16 + l15), dims [kk*128 + l4*32, +32)
// — the 16x16x128 B operand convention verified r8-r13.
// prep writes it, gemm reads it (rule #21: one convention, both sides).
// ---------------------------------------------------------------------------

// ---------------------------------------------------------------------------
// Kernel 1: normalize rows; emit fp8 e4m3 (OCP, HW cvt):
//   qs8  [8192][256] fp8: normalized q scaled by C_SC (MFMA A), natural.
//   keys8: fragment-linear (above). Keys 0..8191 = q, 8192..16383 = g.
//   Pterm[row] = dot_f32(q,g)/T ; diagsub[row] = exp2 of fp8-level qq diag.
// Also zeroes S and out[0].
// ---------------------------------------------------------------------------
__global__ __launch_bounds__(256) void prep_kernel(
    const float* __restrict__ h, const float* __restrict__ g,
    unsigned int* __restrict__ qs8, unsigned int* __restrict__ keys8,
    float* __restrict__ Pterm, float* __restrict__ diagsub,
    float* __restrict__ S, float* __restrict__ out)
{
  const int row  = blockIdx.x * 4 + (threadIdx.x >> 6);
  const int lane = threadIdx.x & 63;       // 4 dims each
  float4_ hv = *((const float4_*)h + row * 64 + lane);
  float4_ gv = *((const float4_*)g + row * 64 + lane);

  float ssh = hv.x*hv.x + hv.y*hv.y + hv.z*hv.z + hv.w*hv.w;
  float ssg = gv.x*gv.x + gv.y*gv.y + gv.z*gv.z + gv.w*gv.w;
#pragma unroll
  for (int m = 1; m < 64; m <<= 1) {
    ssh += __shfl_xor(ssh, m);
    ssg += __shfl_xor(ssg, m);
  }
  const float sh = 1.0f / fmaxf(sqrtf(ssh), 1e-8f);
  const float sg = 1.0f / fmaxf(sqrtf(ssg), 1e-8f);

  float qn[4] = { hv.x*sh, hv.y*sh, hv.z*sh, hv.w*sh };
  float gn[4] = { gv.x*sg, gv.y*sg, gv.z*sg, gv.w*sg };

  float pd = qn[0]*gn[0] + qn[1]*gn[1] + qn[2]*gn[2] + qn[3]*gn[3];

  // fp8 packs (RNE, saturating). word_sel / byte_sel must be literals.
  int pq = __builtin_amdgcn_cvt_pk_fp8_f32(qn[0], qn[1], 0, 0);
  pq     = __builtin_amdgcn_cvt_pk_fp8_f32(qn[2], qn[3], pq, 1);
  int ps = __builtin_amdgcn_cvt_pk_fp8_f32(qn[0]*C_SC, qn[1]*C_SC, 0, 0);
  ps     = __builtin_amdgcn_cvt_pk_fp8_f32(qn[2]*C_SC, qn[3]*C_SC, ps, 1);
  int pg = __builtin_amdgcn_cvt_pk_fp8_f32(gn[0], gn[1], 0, 0);
  pg     = __builtin_amdgcn_cvt_pk_fp8_f32(gn[2], gn[3], pg, 1);

  float dd =
      __builtin_amdgcn_cvt_f32_fp8(ps, 0) * __builtin_amdgcn_cvt_f32_fp8(pq, 0)
    + __builtin_amdgcn_cvt_f32_fp8(ps, 1) * __builtin_amdgcn_cvt_f32_fp8(pq, 1)
    + __builtin_amdgcn_cvt_f32_fp8(ps, 2) * __builtin_amdgcn_cvt_f32_fp8(pq, 2)
    + __builtin_amdgcn_cvt_f32_fp8(ps, 3) * __builtin_amdgcn_cvt_f32_fp8(pq, 3);

#pragma unroll
  for (int m = 1; m < 64; m <<= 1) {
    pd += __shfl_xor(pd, m);
    dd += __shfl_xor(dd, m);
  }

  qs8[(size_t)row * 64 + lane] = (unsigned int)ps;   // natural, coalesced

  // fragment-linear key writes: this lane's dword = dims [lane*4, lane*4+4)
  // kk = lane>>5 ; l4 = (lane>>3)&3 ; inner byte = (lane&7)*4
  char* kb = (char*)keys8;
  const int foff = ((lane >> 5) << 11) + (((lane >> 3) & 3) << 9)
                 + ((lane & 7) << 2);
  {
    const int k = row;                     // q keys
    *(unsigned int*)(kb + (((size_t)(k >> 4)) << 12) + foff
                     + ((k & 15) << 5)) = (unsigned int)pq;
  }
  {
    const int k = NROWS + row;             // g keys
    *(unsigned int*)(kb + (((size_t)(k >> 4)) << 12) + foff
                     + ((k & 15) << 5)) = (unsigned int)pg;
  }

  if (lane == 0) {
    Pterm[row]   = pd * T_INV;
    diagsub[row] = __builtin_amdgcn_exp2f(dd);
    S[row]       = 0.0f;
    if (row == 0) out[0] = 0.0f;           // finalize accumulates atomically
  }
}

// ---------------------------------------------------------------------------
// Kernel 2: fused MX-fp8 GEMM (K=128/instr) + exp2 + row-sum — no LDS
// staging, no main-loop barriers (r13 structure).
// vs r13: mf 8->4 (BM=64/block) halves per-wave state to ~124 combined
// regs -> 4 waves/SIMD (16 waves/CU, 2 blocks/CU). r13 diagnosis: matrix
// 34% + VALU 28% + ~40% dual-idle (L2 latency) at only 2 phase-locked
// waves/SIMD — TLP, not structure, is the binding constraint (m114:
// MFMA/VALU co-schedule across waves when waves exist).
// Cost: B-traffic 32->64 MB/XCD (~1KB/cy at target wall vs 1.9KB/cy L2
// ceiling — accepted). Grid 512 = 128 mtiles x 4 slices; slice = bid&3.
// ---------------------------------------------------------------------------
__global__ __launch_bounds__(512, 4) void nce_gemm(
    const unsigned int* __restrict__ qs8,
    const unsigned int* __restrict__ keys8,
    float* __restrict__ S)
{
  __shared__ float sred[64];               // end-of-kernel reduce only

  const int tid  = threadIdx.x;
  const int wid  = tid >> 6;
  const int lane = tid & 63;
  const int l15  = lane & 15, l4 = lane >> 4;

  const int bid   = blockIdx.x;
  const int slice = bid & 3;               // constant per XCD
  const int mtile = bid >> 2;              // 0..127
  const int m0    = mtile * 64;            // all 8 waves share these 64 rows

  if (tid < 64) sred[tid] = 0.0f;

  // ---- A fragments: 4 mf x 2 kk x 32B ; K elem = kk*128 + l4*32 + j ----
  const char* qb = (const char*)qs8;
  i32x8 a8[4][2];
#pragma unroll
  for (int mf = 0; mf < 4; ++mf) {
    const char* rp = qb + (size_t)(m0 + mf * 16 + l15) * 256 + l4 * 32;
#pragma unroll
    for (int kk = 0; kk < 2; ++kk)
      a8[mf][kk] = *(const i32x8*)(rp + kk * 128);
  }

  const f32x4 zero4 = { 0.f, 0.f, 0.f, 0.f };
  f32x4 acc[4];
  float Sp[4][4] = {};                     // [mf][q] row-sums

  // wave's private key range: 512 keys = 32 groups of 16
  const char* kp = (const char*)keys8
      + (((size_t)(slice * 256 + wid * 32)) << 12) + (size_t)lane * 32;

#pragma unroll 2
  for (int g = 0; g < 32; ++g) {
    i32x8 b0 = *(const i32x8*)(kp + ((size_t)g << 12));
    i32x8 b1 = *(const i32x8*)(kp + ((size_t)g << 12) + 2048);

    if (g > 0) {                           // harvest prev group (old acc)
#pragma unroll
      for (int mf = 0; mf < 4; ++mf)
#pragma unroll
        for (int q = 0; q < 4; ++q)
          Sp[mf][q] += __builtin_amdgcn_exp2f(acc[mf][q]);
    }

    // cbsz=0 (A fmt fp8 e4m3), blgp=0 (B fmt fp8), scales 127 = x1.0
#pragma unroll
    for (int mf = 0; mf < 4; ++mf) {
      f32x4 t = __builtin_amdgcn_mfma_scale_f32_16x16x128_f8f6f4(
          a8[mf][0], b0, zero4, 0, 0, 0, 127, 0, 127);
      acc[mf] = __builtin_amdgcn_mfma_scale_f32_16x16x128_f8f6f4(
          a8[mf][1], b1, t, 0, 0, 0, 127, 0, 127);
    }
  }
#pragma unroll
  for (int mf = 0; mf < 4; ++mf)           // last group's harvest
#pragma unroll
    for (int q = 0; q < 4; ++q)
      Sp[mf][q] += __builtin_amdgcn_exp2f(acc[mf][q]);

  // reduce across the 16 key-columns (lanes sharing l4)
#pragma unroll
  for (int mf = 0; mf < 4; ++mf)
#pragma unroll
    for (int q = 0; q < 4; ++q) {
      float v = Sp[mf][q];
      v += __shfl_xor(v, 1); v += __shfl_xor(v, 2);
      v += __shfl_xor(v, 4); v += __shfl_xor(v, 8);
      Sp[mf][q] = v;
    }

  // block-level reduce in LDS (8 waves share the same 64 rows), then
  // one global atomic per row (4 slices -> 4 atomics/row total).
  __syncthreads();                         // sred init visible
  if (l15 == 0) {
#pragma unroll
    for (int mf = 0; mf < 4; ++mf)
#pragma unroll
      for (int q = 0; q < 4; ++q)
        atomicAdd(&sred[mf * 16 + l4 * 4 + q], Sp[mf][q]);
  }
  __syncthreads();
  if (tid < 64) atomicAdd(&S[m0 + tid], sred[tid]);
}

// ---------------------------------------------------------------------------
// Kernel 3: loss partials -> atomicAdd(out). 32 blocks x 256 thr = 1 row/thr.
// ---------------------------------------------------------------------------
__global__ __launch_bounds__(256) void finalize_kernel(
    const float* __restrict__ S, const float* __restrict__ Pterm,
    const float* __restrict__ diagsub, float* __restrict__ out)
{
  const int i = blockIdx.x * 256 + threadIdx.x;
  float v = S[i] - diagsub[i];
  float acc = logf(fmaxf(v, 1e-20f)) - Pterm[i];
#pragma unroll
  for (int m = 1; m < 64; m <<= 1) acc += __shfl_xor(acc, m);
  __shared__ float w[4];
  if ((threadIdx.x & 63) == 0) w[threadIdx.x >> 6] = acc;
  __syncthreads();
  if (threadIdx.x == 0)
    atomicAdd(out, (w[0] + w[1] + w[2] + w[3]) * (1.0f / (float)NROWS));
}

// ---------------------------------------------------------------------------
extern "C" void kernel_launch(void* const* d_in, const int* in_sizes, int n_in,
                              void* d_out, int out_size, void* d_ws, size_t ws_size,
                              hipStream_t stream) {
  const float* h  = (const float*)d_in[0];
  const float* hg = (const float*)d_in[1];

  char* ws = (char*)d_ws;
  const size_t OFF_QS   = 0;                      // 2 MB (8192*256 fp8)
  const size_t OFF_KEYS = (size_t)2 << 20;        // 4 MB (16384*256 fp8)
  const size_t OFF_P    = (size_t)6 << 20;        // 32 KB
  const size_t OFF_DIAG = OFF_P + 32 * 1024;      // 32 KB
  const size_t OFF_S    = OFF_DIAG + 32 * 1024;   // 32 KB
  const size_t NEED     = OFF_S + 32 * 1024;
  if (ws_size < NEED) return;

  unsigned int* qs8   = (unsigned int*)(ws + OFF_QS);
  unsigned int* keys8 = (unsigned int*)(ws + OFF_KEYS);
  float* Pterm   = (float*)(ws + OFF_P);
  float* diagsub = (float*)(ws + OFF_DIAG);
  float* S       = (float*)(ws + OFF_S);

  prep_kernel<<<2048, 256, 0, stream>>>(h, hg, qs8, keys8, Pterm, diagsub, S,
                                        (float*)d_out);
  nce_gemm<<<512, 512, 0, stream>>>(qs8, keys8, S);
  finalize_kernel<<<32, 256, 0, stream>>>(S, Pterm, diagsub, (float*)d_out);
}